// Round 3
// baseline (51.189 us; speedup 1.0000x reference)
//
#include <hip/hip_runtime.h>
#include <math.h>

#define HH 256
#define WW 256
#define NTHREADS 256
#define HWPIX (HH * WW)
#define PSTRIDE 16   // floats per gaussian param record (64 B, one K$ line)

typedef float f2 __attribute__((ext_vector_type(2)));

// ---------------------------------------------------------------------------
// Precompute: one thread per gaussian. Project, validate, expand the exponent
//   log2(alpha_pre) = A*(x^2+y^2) + B*x + C*y + D
// A=coef, B=-2*coef*u, C=-2*coef*v, D=coef*(u^2+v^2)+log2(op).
// Invalid -> A=B=C=0, D=-inf (exp2 -> +0, no NaN possible).
// Record layout (floats): [A,B,C,D][1,r,g,b][z,0,-,-][----]
// ---------------------------------------------------------------------------
__global__ __launch_bounds__(NTHREADS) void precompute_kernel(
    const float* __restrict__ means,
    const float* __restrict__ colors,
    const float* __restrict__ opacity,
    const float* __restrict__ scales,
    const float* __restrict__ K,
    const float* __restrict__ M,
    float* __restrict__ params,
    int N)
{
    const int n = blockIdx.x * NTHREADS + threadIdx.x;
    if (n >= N) return;

    const float wx = means[3 * n + 0];
    const float wy = means[3 * n + 1];
    const float wz = means[3 * n + 2];
    const float px = M[0] * wx + M[1] * wy + M[2]  * wz + M[3];
    const float py = M[4] * wx + M[5] * wy + M[6]  * wz + M[7];
    const float pz = M[8] * wx + M[9] * wy + M[10] * wz + M[11];
    const float rz = 1.0f / pz;
    const float u = (K[0] * px + K[1] * py + K[2] * pz) * rz;
    const float v = (K[4] * py + K[5] * pz) * rz;
    const bool valid = (pz > 1e-4f)
                    && (u >= -(float)WW) && (u <= 2.0f * (float)WW)
                    && (v >= -(float)HH) && (v <= 2.0f * (float)HH);
    const float op  = valid ? opacity[n] : 0.0f;
    const float sig = fmaxf(scales[n] * 256.0f, 1.0f);   // max(H,W)=256
    const float coef = -0.72134752044448170368f / (sig * sig); // -0.5*log2e/sig^2

    float A, B, C, D;
    if (valid) {
        A = coef;
        B = -2.0f * coef * u;
        C = -2.0f * coef * v;
        D = fmaf(coef, fmaf(u, u, v * v), __log2f(op));  // op=0 -> -inf
    } else {
        A = 0.f; B = 0.f; C = 0.f; D = -INFINITY;
    }

    float4* o = (float4*)(params + (size_t)n * PSTRIDE);
    o[0] = make_float4(A, B, C, D);
    o[1] = make_float4(1.0f, colors[3 * n + 0], colors[3 * n + 1], colors[3 * n + 2]);
    o[2] = make_float4(pz, 0.0f, 0.0f, 0.0f);
}

// ---------------------------------------------------------------------------
// Partial sums: blockIdx.x = image row (256 px), blockIdx.y = gaussian slice.
// Per-gaussian params are read at a wave-uniform address -> s_load (SGPRs),
// so the hot loop has NO LDS and ~9 VALU + 1 trans per gaussian.
// ---------------------------------------------------------------------------
__global__ __launch_bounds__(NTHREADS) void partial_kernel(
    const float* __restrict__ params,
    float* __restrict__ outp,
    int N, int nslice)
{
    const int tid = threadIdx.x;
    const int p   = blockIdx.x * NTHREADS + tid;
    const float x = (float)tid;          // W == NTHREADS == 256
    const float y = (float)blockIdx.x;
    const float xy2 = fmaf(x, x, y * y);

    const int chunk = (N + nslice - 1) / nslice;
    const int g0 = blockIdx.y * chunk;
    const int g1 = min(N, g0 + chunk);

    f2 acc0 = {0.f, 0.f};   // (S, sum a*r)
    f2 acc1 = {0.f, 0.f};   // (sum a*g, sum a*b)
    f2 acc2 = {0.f, 0.f};   // (sum a*z, 0)

    #pragma unroll 4
    for (int n = g0; n < g1; ++n) {
        const float* g = params + (size_t)n * PSTRIDE;
        float t = fmaf(x, g[1], g[0] * xy2);
        t = fmaf(y, g[2], t);
        t = t + g[3];
        const float e = exp2f(t);
        const float alpha = fminf(e, 0.95f);
        const f2 a2 = {alpha, alpha};
        acc0 = __builtin_elementwise_fma(a2, *(const f2*)(g + 4), acc0);
        acc1 = __builtin_elementwise_fma(a2, *(const f2*)(g + 6), acc1);
        acc2 = __builtin_elementwise_fma(a2, *(const f2*)(g + 8), acc2);
    }

    float* o = outp + (size_t)(blockIdx.y * 5) * HWPIX + p;
    o[0 * HWPIX] = acc0.x;
    o[1 * HWPIX] = acc0.y;
    o[2 * HWPIX] = acc1.x;
    o[3 * HWPIX] = acc1.y;
    o[4 * HWPIX] = acc2.x;
}

// ---------------------------------------------------------------------------
// Epilogue: reduce slices, normalize, composite background, clip, store.
// ---------------------------------------------------------------------------
__global__ __launch_bounds__(NTHREADS) void epilogue_kernel(
    const float* __restrict__ outp, float* __restrict__ out, int nslice)
{
    const int p = blockIdx.x * NTHREADS + threadIdx.x;
    float s = 0.f, ar = 0.f, ag = 0.f, ab = 0.f, az = 0.f;
    for (int sl = 0; sl < nslice; ++sl) {
        const float* o = outp + (size_t)(sl * 5) * HWPIX + p;
        s  += o[0 * HWPIX];
        ar += o[1 * HWPIX];
        ag += o[2 * HWPIX];
        ab += o[3 * HWPIX];
        az += o[4 * HWPIX];
    }
    const float inv   = 1.0f / (s + 1e-6f);
    const float accum = fminf(s, 1.0f);
    const float bg    = 1.0f - accum;
    out[0 * HWPIX + p] = fminf(fmaxf(fmaf(ar * inv, accum, bg), 0.0f), 1.0f);
    out[1 * HWPIX + p] = fminf(fmaxf(fmaf(ag * inv, accum, bg), 0.0f), 1.0f);
    out[2 * HWPIX + p] = fminf(fmaxf(fmaf(ab * inv, accum, bg), 0.0f), 1.0f);
    out[3 * HWPIX + p] = accum;
    out[4 * HWPIX + p] = az * inv;
}

// ---------------------------------------------------------------------------
// Fallback fused kernel (only if ws is too small — LDS-staged, self-contained)
// ---------------------------------------------------------------------------
__global__ __launch_bounds__(NTHREADS) void fused_kernel(
    const float* __restrict__ means,
    const float* __restrict__ colors,
    const float* __restrict__ opacity,
    const float* __restrict__ scales,
    const float* __restrict__ K,
    const float* __restrict__ M,
    float* __restrict__ out,
    int N)
{
    __shared__ float4 sg[256 * 2];
    const int tid = threadIdx.x;
    const int p   = blockIdx.x * NTHREADS + tid;
    const float x = (float)(p & (WW - 1));
    const float y = (float)(p >> 8);
    const float fx = K[0], sk = K[1], cx = K[2], fy = K[4], cy = K[5];

    float s = 0.f, ar = 0.f, ag = 0.f, ab = 0.f, az = 0.f;
    for (int base = 0; base < N; base += 256) {
        const int cnt = min(256, N - base);
        __syncthreads();
        for (int i = tid; i < cnt; i += NTHREADS) {
            const int n = base + i;
            const float wx = means[3 * n + 0];
            const float wy = means[3 * n + 1];
            const float wz = means[3 * n + 2];
            const float px = M[0] * wx + M[1] * wy + M[2]  * wz + M[3];
            const float py = M[4] * wx + M[5] * wy + M[6]  * wz + M[7];
            const float pz = M[8] * wx + M[9] * wy + M[10] * wz + M[11];
            const float rz = 1.0f / pz;
            float u = (fx * px + sk * py + cx * pz) * rz;
            float v = (fy * py + cy * pz) * rz;
            const bool valid = (pz > 1e-4f)
                            && (u >= -(float)WW) && (u <= 2.0f * (float)WW)
                            && (v >= -(float)HH) && (v <= 2.0f * (float)HH);
            const float op = valid ? opacity[n] : 0.0f;
            const float sig = fmaxf(scales[n] * 256.0f, 1.0f);
            float coef = -0.72134752044448170368f / (sig * sig);
            const float lop = __log2f(op);
            if (!valid) { u = 0.f; v = 0.f; coef = 0.f; }
            sg[2 * i + 0] = make_float4(u, v, coef, lop);
            sg[2 * i + 1] = make_float4(colors[3 * n + 0], colors[3 * n + 1],
                                        colors[3 * n + 2], pz);
        }
        __syncthreads();
        for (int n = 0; n < cnt; ++n) {
            const float4 a = sg[2 * n + 0];
            const float4 c = sg[2 * n + 1];
            const float dx = x - a.x, dy = y - a.y;
            const float r2 = fmaf(dy, dy, dx * dx);
            const float alpha = fminf(exp2f(fmaf(r2, a.z, a.w)), 0.95f);
            s += alpha;
            ar = fmaf(alpha, c.x, ar); ag = fmaf(alpha, c.y, ag);
            ab = fmaf(alpha, c.z, ab); az = fmaf(alpha, c.w, az);
        }
    }
    const float inv   = 1.0f / (s + 1e-6f);
    const float accum = fminf(s, 1.0f);
    const float bg    = 1.0f - accum;
    out[0 * HWPIX + p] = fminf(fmaxf(fmaf(ar * inv, accum, bg), 0.0f), 1.0f);
    out[1 * HWPIX + p] = fminf(fmaxf(fmaf(ag * inv, accum, bg), 0.0f), 1.0f);
    out[2 * HWPIX + p] = fminf(fmaxf(fmaf(ab * inv, accum, bg), 0.0f), 1.0f);
    out[3 * HWPIX + p] = accum;
    out[4 * HWPIX + p] = az * inv;
}

extern "C" void kernel_launch(void* const* d_in, const int* in_sizes, int n_in,
                              void* d_out, int out_size, void* d_ws, size_t ws_size,
                              hipStream_t stream) {
    const float* means      = (const float*)d_in[0];
    const float* colors     = (const float*)d_in[1];
    const float* opacity    = (const float*)d_in[2];
    const float* scales     = (const float*)d_in[3];
    const float* intrinsics = (const float*)d_in[4];
    const float* w2c        = (const float*)d_in[5];
    float* out = (float*)d_out;
    float* ws  = (float*)d_ws;

    const int N = in_sizes[0] / 3;
    const int npixblocks = HWPIX / NTHREADS;          // 256
    const size_t param_floats = (size_t)N * PSTRIDE;

    int nslice = 8;
    while (nslice > 1 &&
           (param_floats + (size_t)nslice * 5 * HWPIX) * 4 > ws_size)
        nslice >>= 1;

    if ((param_floats + (size_t)5 * HWPIX) * 4 > ws_size) {
        fused_kernel<<<npixblocks, NTHREADS, 0, stream>>>(
            means, colors, opacity, scales, intrinsics, w2c, out, N);
        return;
    }

    float* partials = ws + param_floats;

    precompute_kernel<<<(N + NTHREADS - 1) / NTHREADS, NTHREADS, 0, stream>>>(
        means, colors, opacity, scales, intrinsics, w2c, ws, N);
    partial_kernel<<<dim3(npixblocks, nslice), NTHREADS, 0, stream>>>(
        ws, partials, N, nslice);
    epilogue_kernel<<<npixblocks, NTHREADS, 0, stream>>>(partials, out, nslice);
}

// Round 4
// 45.103 us; speedup vs baseline: 1.1349x; 1.1349x over previous
//
#include <hip/hip_runtime.h>
#include <math.h>

#define HH 256
#define WW 256
#define NTHREADS 256
#define ROWSPB 4         // pixels (rows) per thread
#define MAXCHUNK 64      // gaussians staged per block iteration
#define NSLICE 16
#define HWPIX (HH * WW)

typedef float f2 __attribute__((ext_vector_type(2)));

// ---------------------------------------------------------------------------
// Partial sums. blockIdx.x = row group (4 rows x 256 cols), blockIdx.y =
// gaussian slice. Thread t = column x, covering 4 rows. Staging projects each
// gaussian and expands the exponent per-row:
//   log2(alpha) = (A*x + B)*x + E(y),  E(y) = (A*y + C)*y + D
//   A=coef, B=-2*coef*u, C=-2*coef*v, D=coef*(u^2+v^2)+log2(op)
// Invalid gaussian -> A=B=C=0, D=-inf (exp2 -> +0, no NaN).
// LDS record (12 floats): [A,B,E0,E1][E2,E3,1,r][g,b,z,0]
// One record read (3 x ds_read_b128) serves 4 gaussian-pixel pairs.
// ---------------------------------------------------------------------------
__global__ __launch_bounds__(NTHREADS) void partial_kernel(
    const float* __restrict__ means,
    const float* __restrict__ colors,
    const float* __restrict__ opacity,
    const float* __restrict__ scales,
    const float* __restrict__ K,
    const float* __restrict__ M,
    float* __restrict__ outp,
    int N, int nslice)
{
    __shared__ float4 sg[MAXCHUNK * 3];

    const int tid = threadIdx.x;
    const float xf = (float)tid;
    const float y0f = (float)(blockIdx.x * ROWSPB);

    const int chunk = (N + nslice - 1) / nslice;
    const int g0 = blockIdx.y * chunk;
    const int g1 = min(N, g0 + chunk);

    f2 acc[ROWSPB][3];
    #pragma unroll
    for (int i = 0; i < ROWSPB; ++i) {
        acc[i][0] = (f2){0.f, 0.f};   // (S, sum a*r)
        acc[i][1] = (f2){0.f, 0.f};   // (sum a*g, sum a*b)
        acc[i][2] = (f2){0.f, 0.f};   // (sum a*z, 0)
    }

    for (int base = g0; base < g1; base += MAXCHUNK) {
        const int cnt = min(MAXCHUNK, g1 - base);

        __syncthreads();
        if (tid < cnt) {
            const int n = base + tid;
            const float wx = means[3 * n + 0];
            const float wy = means[3 * n + 1];
            const float wz = means[3 * n + 2];
            const float px = M[0] * wx + M[1] * wy + M[2]  * wz + M[3];
            const float py = M[4] * wx + M[5] * wy + M[6]  * wz + M[7];
            const float pz = M[8] * wx + M[9] * wy + M[10] * wz + M[11];
            const float rz = 1.0f / pz;
            const float u = (K[0] * px + K[1] * py + K[2] * pz) * rz;
            const float v = (K[4] * py + K[5] * pz) * rz;
            const bool valid = (pz > 1e-4f)
                            && (u >= -(float)WW) && (u <= 2.0f * (float)WW)
                            && (v >= -(float)HH) && (v <= 2.0f * (float)HH);
            const float op  = valid ? opacity[n] : 0.0f;
            const float sig = fmaxf(scales[n] * 256.0f, 1.0f);
            const float coef = -0.72134752044448170368f / (sig * sig);

            float A, B, C, D;
            if (valid) {
                A = coef;
                B = -2.0f * coef * u;
                C = -2.0f * coef * v;
                D = fmaf(coef, fmaf(u, u, v * v), __log2f(op)); // op=0 -> -inf
            } else {
                A = 0.f; B = 0.f; C = 0.f; D = -INFINITY;
            }
            float E[ROWSPB];
            #pragma unroll
            for (int i = 0; i < ROWSPB; ++i) {
                const float yi = y0f + (float)i;
                E[i] = fmaf(fmaf(A, yi, C), yi, D);
            }
            sg[3 * tid + 0] = make_float4(A, B, E[0], E[1]);
            sg[3 * tid + 1] = make_float4(E[2], E[3], 1.0f, colors[3 * n + 0]);
            sg[3 * tid + 2] = make_float4(colors[3 * n + 1], colors[3 * n + 2],
                                          pz, 0.0f);
        }
        __syncthreads();

        #pragma unroll 4
        for (int n = 0; n < cnt; ++n) {
            const float4 r0 = sg[3 * n + 0];
            const float4 r1 = sg[3 * n + 1];
            const float4 r2 = sg[3 * n + 2];
            const float q = fmaf(r0.x, xf, r0.y);       // A*x + B (shared by 4 rows)
            float a0 = fminf(exp2f(fmaf(q, xf, r0.z)), 0.95f);
            float a1 = fminf(exp2f(fmaf(q, xf, r0.w)), 0.95f);
            float a2 = fminf(exp2f(fmaf(q, xf, r1.x)), 0.95f);
            float a3 = fminf(exp2f(fmaf(q, xf, r1.y)), 0.95f);
            const f2 c0 = {r1.z, r1.w};   // (1, r)
            const f2 c1 = {r2.x, r2.y};   // (g, b)
            const f2 c2 = {r2.z, r2.w};   // (z, 0)
            acc[0][0] = __builtin_elementwise_fma((f2){a0, a0}, c0, acc[0][0]);
            acc[0][1] = __builtin_elementwise_fma((f2){a0, a0}, c1, acc[0][1]);
            acc[0][2] = __builtin_elementwise_fma((f2){a0, a0}, c2, acc[0][2]);
            acc[1][0] = __builtin_elementwise_fma((f2){a1, a1}, c0, acc[1][0]);
            acc[1][1] = __builtin_elementwise_fma((f2){a1, a1}, c1, acc[1][1]);
            acc[1][2] = __builtin_elementwise_fma((f2){a1, a1}, c2, acc[1][2]);
            acc[2][0] = __builtin_elementwise_fma((f2){a2, a2}, c0, acc[2][0]);
            acc[2][1] = __builtin_elementwise_fma((f2){a2, a2}, c1, acc[2][1]);
            acc[2][2] = __builtin_elementwise_fma((f2){a2, a2}, c2, acc[2][2]);
            acc[3][0] = __builtin_elementwise_fma((f2){a3, a3}, c0, acc[3][0]);
            acc[3][1] = __builtin_elementwise_fma((f2){a3, a3}, c1, acc[3][1]);
            acc[3][2] = __builtin_elementwise_fma((f2){a3, a3}, c2, acc[3][2]);
        }
    }

    float* o = outp + ((size_t)blockIdx.y * 5) * HWPIX
                    + (size_t)(blockIdx.x * ROWSPB) * WW + tid;
    #pragma unroll
    for (int i = 0; i < ROWSPB; ++i) {
        o[0 * HWPIX + i * WW] = acc[i][0].x;
        o[1 * HWPIX + i * WW] = acc[i][0].y;
        o[2 * HWPIX + i * WW] = acc[i][1].x;
        o[3 * HWPIX + i * WW] = acc[i][1].y;
        o[4 * HWPIX + i * WW] = acc[i][2].x;
    }
}

// ---------------------------------------------------------------------------
// Epilogue: reduce slices, normalize, composite background, clip, store.
// ---------------------------------------------------------------------------
__global__ __launch_bounds__(NTHREADS) void epilogue_kernel(
    const float* __restrict__ outp, float* __restrict__ out, int nslice)
{
    const int p = blockIdx.x * NTHREADS + threadIdx.x;
    float s = 0.f, ar = 0.f, ag = 0.f, ab = 0.f, az = 0.f;
    for (int sl = 0; sl < nslice; ++sl) {
        const float* o = outp + (size_t)(sl * 5) * HWPIX + p;
        s  += o[0 * HWPIX];
        ar += o[1 * HWPIX];
        ag += o[2 * HWPIX];
        ab += o[3 * HWPIX];
        az += o[4 * HWPIX];
    }
    const float inv   = 1.0f / (s + 1e-6f);
    const float accum = fminf(s, 1.0f);
    const float bg    = 1.0f - accum;
    out[0 * HWPIX + p] = fminf(fmaxf(fmaf(ar * inv, accum, bg), 0.0f), 1.0f);
    out[1 * HWPIX + p] = fminf(fmaxf(fmaf(ag * inv, accum, bg), 0.0f), 1.0f);
    out[2 * HWPIX + p] = fminf(fmaxf(fmaf(ab * inv, accum, bg), 0.0f), 1.0f);
    out[3 * HWPIX + p] = accum;
    out[4 * HWPIX + p] = az * inv;
}

// ---------------------------------------------------------------------------
// Fallback fused kernel (only if ws is too small) — known-good round-2 path.
// ---------------------------------------------------------------------------
__global__ __launch_bounds__(NTHREADS) void fused_kernel(
    const float* __restrict__ means,
    const float* __restrict__ colors,
    const float* __restrict__ opacity,
    const float* __restrict__ scales,
    const float* __restrict__ K,
    const float* __restrict__ M,
    float* __restrict__ out,
    int N)
{
    __shared__ float4 sg[256 * 2];
    const int tid = threadIdx.x;
    const int p   = blockIdx.x * NTHREADS + tid;
    const float x = (float)(p & (WW - 1));
    const float y = (float)(p >> 8);
    const float fx = K[0], sk = K[1], cx = K[2], fy = K[4], cy = K[5];

    float s = 0.f, ar = 0.f, ag = 0.f, ab = 0.f, az = 0.f;
    for (int base = 0; base < N; base += 256) {
        const int cnt = min(256, N - base);
        __syncthreads();
        for (int i = tid; i < cnt; i += NTHREADS) {
            const int n = base + i;
            const float wx = means[3 * n + 0];
            const float wy = means[3 * n + 1];
            const float wz = means[3 * n + 2];
            const float px = M[0] * wx + M[1] * wy + M[2]  * wz + M[3];
            const float py = M[4] * wx + M[5] * wy + M[6]  * wz + M[7];
            const float pz = M[8] * wx + M[9] * wy + M[10] * wz + M[11];
            const float rz = 1.0f / pz;
            float u = (fx * px + sk * py + cx * pz) * rz;
            float v = (fy * py + cy * pz) * rz;
            const bool valid = (pz > 1e-4f)
                            && (u >= -(float)WW) && (u <= 2.0f * (float)WW)
                            && (v >= -(float)HH) && (v <= 2.0f * (float)HH);
            const float op = valid ? opacity[n] : 0.0f;
            const float sig = fmaxf(scales[n] * 256.0f, 1.0f);
            float coef = -0.72134752044448170368f / (sig * sig);
            const float lop = __log2f(op);
            float uu = valid ? u : 0.f, vv = valid ? v : 0.f;
            float cf = valid ? coef : 0.f;
            sg[2 * i + 0] = make_float4(uu, vv, cf, lop);
            sg[2 * i + 1] = make_float4(colors[3 * n + 0], colors[3 * n + 1],
                                        colors[3 * n + 2], pz);
        }
        __syncthreads();
        for (int n = 0; n < cnt; ++n) {
            const float4 a = sg[2 * n + 0];
            const float4 c = sg[2 * n + 1];
            const float dx = x - a.x, dy = y - a.y;
            const float r2 = fmaf(dy, dy, dx * dx);
            const float alpha = fminf(exp2f(fmaf(r2, a.z, a.w)), 0.95f);
            s += alpha;
            ar = fmaf(alpha, c.x, ar); ag = fmaf(alpha, c.y, ag);
            ab = fmaf(alpha, c.z, ab); az = fmaf(alpha, c.w, az);
        }
    }
    const float inv   = 1.0f / (s + 1e-6f);
    const float accum = fminf(s, 1.0f);
    const float bg    = 1.0f - accum;
    out[0 * HWPIX + p] = fminf(fmaxf(fmaf(ar * inv, accum, bg), 0.0f), 1.0f);
    out[1 * HWPIX + p] = fminf(fmaxf(fmaf(ag * inv, accum, bg), 0.0f), 1.0f);
    out[2 * HWPIX + p] = fminf(fmaxf(fmaf(ab * inv, accum, bg), 0.0f), 1.0f);
    out[3 * HWPIX + p] = accum;
    out[4 * HWPIX + p] = az * inv;
}

extern "C" void kernel_launch(void* const* d_in, const int* in_sizes, int n_in,
                              void* d_out, int out_size, void* d_ws, size_t ws_size,
                              hipStream_t stream) {
    const float* means      = (const float*)d_in[0];
    const float* colors     = (const float*)d_in[1];
    const float* opacity    = (const float*)d_in[2];
    const float* scales     = (const float*)d_in[3];
    const float* intrinsics = (const float*)d_in[4];
    const float* w2c        = (const float*)d_in[5];
    float* out = (float*)d_out;
    float* ws  = (float*)d_ws;

    const int N = in_sizes[0] / 3;

    int nslice = NSLICE;
    while (nslice > 1 && (size_t)nslice * 5 * HWPIX * 4 > ws_size) nslice >>= 1;

    if ((size_t)5 * HWPIX * 4 > ws_size) {
        fused_kernel<<<HWPIX / NTHREADS, NTHREADS, 0, stream>>>(
            means, colors, opacity, scales, intrinsics, w2c, out, N);
        return;
    }

    dim3 grid(HH / ROWSPB, nslice);   // 64 x 16 = 1024 blocks
    partial_kernel<<<grid, NTHREADS, 0, stream>>>(
        means, colors, opacity, scales, intrinsics, w2c, ws, N, nslice);
    epilogue_kernel<<<HWPIX / NTHREADS, NTHREADS, 0, stream>>>(ws, out, nslice);
}